// Round 1
// 135.287 us; speedup vs baseline: 1.0875x; 1.0875x over previous
//
#include <hip/hip_runtime.h>
#include <hip/hip_bf16.h>

#define B_ 1024
#define S_ 100
#define IN_ 100
#define H_ 128
#define MID_ 32
#define OUT_ 2
#define P_ (B_ * S_)
#define RSQRT_H 0.08838834764831845f
#define LSTR 136   // LDS row stride in bf16 elems: 272 B -> max 2-way bank conflict (free)
#define MROWS 100  // 6 full M-tiles + overlapped last tile at row 84 (rows 84-95 dup-written)

typedef __attribute__((ext_vector_type(8))) short short8;
typedef __attribute__((ext_vector_type(4))) short short4v;
typedef __attribute__((ext_vector_type(4))) float float4v;

__device__ __forceinline__ float bf2f(ushort u) {
    union { unsigned u; float f; } c; c.u = ((unsigned)u) << 16; return c.f;
}
__device__ __forceinline__ ushort f2bf(float x) {
    union { float f; unsigned u; } c; c.f = x;
    unsigned r = c.u + 0x7FFFu + ((c.u >> 16) & 1u);  // RNE
    return (ushort)(r >> 16);
}

// ---------------------------------------------------------------------------
// Merged prep: blocks 0..143 transpose W1/Wv/W2 -> bf16 [n][k] (k padded 128);
// blocks 144..159 compute WqkT[n][k] = sum_j Wq[k][j]*Wk[n][j] (32x32 tiles).
// One dispatch instead of two serialized launches.
// ---------------------------------------------------------------------------
__global__ __launch_bounds__(256) void prep_kernel(
    const float* __restrict__ W1, const float* __restrict__ Wv,
    const float* __restrict__ W2, const float* __restrict__ Wq,
    const float* __restrict__ Wk,
    ushort* __restrict__ W1T, ushort* __restrict__ WvT,
    ushort* __restrict__ W2T, ushort* __restrict__ WqkT) {
    int tid = threadIdx.x;
    if (blockIdx.x < 144) {
        int g = blockIdx.x * 256 + tid;
        if (g < 16384) {
            int n = g >> 7, k = g & 127;
            W1T[g] = (k < IN_) ? f2bf(W1[k * H_ + n]) : (ushort)0;
        } else if (g < 32768) {
            int e = g - 16384; int n = e >> 7, k = e & 127;
            WvT[e] = f2bf(Wv[k * H_ + n]);
        } else {
            int e = g - 32768; int n = e >> 7, k = e & 127;
            W2T[e] = f2bf(W2[k * MID_ + n]);
        }
    } else {
        __shared__ float sq[32][132];  // Wq rows k0..k0+31 (pad 132 breaks conflicts)
        __shared__ float sk[32][132];  // Wk rows n0..n0+31
        int bid = blockIdx.x - 144;
        int n0 = (bid >> 2) * 32, k0 = (bid & 3) * 32;
        for (int i = tid; i < 32 * 32; i += 256) {
            int r = i >> 5, c4 = (i & 31) * 4;
            float4 a = *(const float4*)(Wq + (k0 + r) * H_ + c4);
            float4 b = *(const float4*)(Wk + (n0 + r) * H_ + c4);
            sq[r][c4] = a.x; sq[r][c4 + 1] = a.y; sq[r][c4 + 2] = a.z; sq[r][c4 + 3] = a.w;
            sk[r][c4] = b.x; sk[r][c4 + 1] = b.y; sk[r][c4 + 2] = b.z; sk[r][c4 + 3] = b.w;
        }
        __syncthreads();
        for (int i = tid; i < 1024; i += 256) {
            int kk = i & 31, nn = i >> 5;
            float a0 = 0.f, a1 = 0.f, a2 = 0.f, a3 = 0.f;
#pragma unroll
            for (int j = 0; j < 128; j += 4) {
                a0 += sq[kk][j + 0] * sk[nn][j + 0];
                a1 += sq[kk][j + 1] * sk[nn][j + 1];
                a2 += sq[kk][j + 2] * sk[nn][j + 2];
                a3 += sq[kk][j + 3] * sk[nn][j + 3];
            }
            WqkT[(n0 + nn) * 128 + (k0 + kk)] = f2bf((a0 + a1) + (a2 + a3));
        }
    }
}

// ---------------------------------------------------------------------------
// Fused per-sequence GEMM stage: C_lds[m][n] = epi(A_lds[m][128] @ WT^T)
// 8 waves, one 16-col N-tile per wave. 7 M-tiles: starts 0,16,..,80,84
// (last tile overlaps rows 84-95 -> identical duplicate writes, benign).
// EPI 0: none | 1: relu(+bias)+pe | 2: +bias
// ---------------------------------------------------------------------------
template <int EPI>
__device__ __forceinline__ void mm_stage(const ushort* __restrict__ A_lds,
                                         const ushort* __restrict__ WT,
                                         ushort* __restrict__ C_lds,
                                         int wave, int lane,
                                         const float* __restrict__ bias,
                                         const float* __restrict__ pe) {
    int l15 = lane & 15, quad = lane >> 4;
    int n = wave * 16 + l15;
    short8 bfrag[4];
#pragma unroll
    for (int ks = 0; ks < 4; ++ks)
        bfrag[ks] = *(const short8*)(WT + n * 128 + ks * 32 + quad * 8);
    float biasv = 0.f;
    if (EPI != 0) biasv = bias[n];
#pragma unroll
    for (int mt = 0; mt < 7; ++mt) {
        int m0 = (mt < 6) ? mt * 16 : 84;
        short8 afrag[4];
#pragma unroll
        for (int ks = 0; ks < 4; ++ks)
            afrag[ks] = *(const short8*)(A_lds + (m0 + l15) * LSTR + ks * 32 + quad * 8);
        float4v acc = {0.f, 0.f, 0.f, 0.f};
#pragma unroll
        for (int ks = 0; ks < 4; ++ks)
            acc = __builtin_amdgcn_mfma_f32_16x16x32_bf16(afrag[ks], bfrag[ks], acc, 0, 0, 0);
#pragma unroll
        for (int i = 0; i < 4; ++i) {
            int row = m0 + quad * 4 + i;
            float v = acc[i];
            if (EPI == 1) v = fmaxf(v + biasv, 0.f) + pe[row * H_ + n];
            else if (EPI == 2) v = v + biasv;
            C_lds[row * LSTR + n] = f2bf(v);
        }
    }
}

// ---------------------------------------------------------------------------
// Megakernel: one block (512 threads, 8 waves) per batch row b.
// ---------------------------------------------------------------------------
__global__ __launch_bounds__(512, 4) void fused_kernel(
    const float* __restrict__ x, const ushort* __restrict__ W1T,
    const ushort* __restrict__ WqkT, const ushort* __restrict__ WvT,
    const ushort* __restrict__ W2T,
    const float* __restrict__ b1, const float* __restrict__ bv,
    const float* __restrict__ b2, const float* __restrict__ W3,
    const float* __restrict__ b3, const float* __restrict__ pe,
    float* __restrict__ out, float* __restrict__ wout) {
    __shared__ ushort klds[MROWS * LSTR];  // x -> kq -> nsum -> mid
    __shared__ ushort xh[MROWS * LSTR];    // h -> ctx
    int tid = threadIdx.x, wave = tid >> 6, lane = tid & 63;
    int b = blockIdx.x;
    const float* xb = x + (size_t)b * (S_ * IN_);

    // load x -> klds as bf16 [m][k] (float4: 25 vec4 per 100-elem row, never
    // crossing rows); zero only the K-pad cols 100..127 (rest fully written)
    for (int i = tid; i < 2500; i += 512) {
        float4 v = ((const float4*)xb)[i];
        int m = i / 25, k4 = (i - m * 25) * 4;
        short4v s;
        s[0] = (short)f2bf(v.x); s[1] = (short)f2bf(v.y);
        s[2] = (short)f2bf(v.z); s[3] = (short)f2bf(v.w);
        *(short4v*)(klds + m * LSTR + k4) = s;
    }
    for (int i = tid; i < S_ * 28; i += 512) {
        int r = i / 28, c = i - r * 28;
        klds[r * LSTR + 100 + c] = 0;
    }
    __syncthreads();
    // S1: h = relu(x@W1 + b1) + pe  -> xh
    mm_stage<1>(klds, W1T, xh, wave, lane, b1, pe);
    __syncthreads();
    // S2: kq = h @ (Wq Wk^T)        -> klds
    mm_stage<0>(xh, WqkT, klds, wave, lane, nullptr, nullptr);
    __syncthreads();
    // S3: scores -> softmax -> w (global) + nsum (in-place over klds rows)
    // 4 threads per row, 32 dims each; quad-reduce via shfl_xor 1,2.
    if (tid < 4 * S_) {
        int r = tid >> 2, q = tid & 3;
        const ushort* kqr = klds + r * LSTR + q * 32;
        float kqf[32];
#pragma unroll
        for (int c = 0; c < 4; ++c) {
            short8 v = *(const short8*)(kqr + c * 8);
#pragma unroll
            for (int j = 0; j < 8; ++j) kqf[c * 8 + j] = bf2f((ushort)v[j]);
        }
        float sc[5];
#pragma unroll
        for (int m = 0; m < 5; ++m) {
            int nr = r + 2 - m;  // neighbor index m == x[i + ATTEN - m]
            float p = 0.f;
            if (nr >= 0 && nr < S_) {
                const ushort* hr = xh + nr * LSTR + q * 32;
#pragma unroll
                for (int c = 0; c < 4; ++c) {
                    short8 v = *(const short8*)(hr + c * 8);
#pragma unroll
                    for (int j = 0; j < 8; ++j) p += bf2f((ushort)v[j]) * kqf[c * 8 + j];
                }
            }
            sc[m] = p;
        }
#pragma unroll
        for (int m = 0; m < 5; ++m) {
            sc[m] += __shfl_xor(sc[m], 1);
            sc[m] += __shfl_xor(sc[m], 2);
            sc[m] *= RSQRT_H;
        }
        float mx = sc[0];
#pragma unroll
        for (int m = 1; m < 5; ++m) mx = fmaxf(mx, sc[m]);
        float e[5], ss = 0.f;
#pragma unroll
        for (int m = 0; m < 5; ++m) { e[m] = expf(sc[m] - mx); ss += e[m]; }
        float inv = 1.f / ss;
        float w5[5];
#pragma unroll
        for (int m = 0; m < 5; ++m) w5[m] = e[m] * inv;
        if (q == 0) {
            float* wp = wout + (size_t)b * (S_ * 5) + r * 5;
#pragma unroll
            for (int m = 0; m < 5; ++m) wp[m] = w5[m];
        }
        // nsum[r] = sum_m w[m] * h[r+2-m]  (bv absorbed post-GEMM; sum w = 1)
        float acc[32];
#pragma unroll
        for (int c = 0; c < 32; ++c) acc[c] = 0.f;
#pragma unroll
        for (int m = 0; m < 5; ++m) {
            int nr = r + 2 - m;
            if (nr < 0 || nr >= S_) continue;
            float wm = w5[m];
            const ushort* hr = xh + nr * LSTR + q * 32;
#pragma unroll
            for (int c = 0; c < 4; ++c) {
                short8 v = *(const short8*)(hr + c * 8);
#pragma unroll
                for (int j = 0; j < 8; ++j) acc[c * 8 + j] += wm * bf2f((ushort)v[j]);
            }
        }
        ushort* op = klds + r * LSTR + q * 32;  // own quarter-row only: race-free
#pragma unroll
        for (int c = 0; c < 4; ++c) {
            short8 v;
#pragma unroll
            for (int j = 0; j < 8; ++j) v[j] = (short)f2bf(acc[c * 8 + j]);
            *(short8*)(op + c * 8) = v;
        }
    }
    __syncthreads();
    // S4: ctx = nsum @ Wv + bv  -> xh
    mm_stage<2>(klds, WvT, xh, wave, lane, bv, nullptr);
    __syncthreads();
    // S5: mid = relu(ctx @ W2 + b2) -> klds cols 0..31 (14 (mt,nt) tasks / 8 waves)
    {
        int l15 = lane & 15, quad = lane >> 4;
        for (int t = wave; t < 14; t += 8) {
            int mt = t >> 1, nt = t & 1;
            int m0 = (mt < 6) ? mt * 16 : 84;
            short8 bfrag[4];
#pragma unroll
            for (int ks = 0; ks < 4; ++ks)
                bfrag[ks] = *(const short8*)(W2T + (nt * 16 + l15) * 128 + ks * 32 + quad * 8);
            float biasv = b2[nt * 16 + l15];
            short8 afrag[4];
#pragma unroll
            for (int ks = 0; ks < 4; ++ks)
                afrag[ks] = *(const short8*)(xh + (m0 + l15) * LSTR + ks * 32 + quad * 8);
            float4v acc = {0.f, 0.f, 0.f, 0.f};
#pragma unroll
            for (int ks = 0; ks < 4; ++ks)
                acc = __builtin_amdgcn_mfma_f32_16x16x32_bf16(afrag[ks], bfrag[ks], acc, 0, 0, 0);
#pragma unroll
            for (int i = 0; i < 4; ++i) {
                int row = m0 + quad * 4 + i;
                klds[row * LSTR + nt * 16 + l15] = f2bf(fmaxf(acc[i] + biasv, 0.f));
            }
        }
    }
    __syncthreads();
    // S6: out = mid @ W3 + b3  (K=32, N=2) -- vector math
    if (tid < S_) {
        int r = tid;
        float o0 = b3[0], o1 = b3[1];
#pragma unroll
        for (int k = 0; k < MID_; ++k) {
            float mv = bf2f(klds[r * LSTR + k]);
            o0 += mv * W3[k * 2];
            o1 += mv * W3[k * 2 + 1];
        }
        float* op = out + (size_t)b * (S_ * OUT_) + r * OUT_;
        op[0] = o0; op[1] = o1;
    }
}

// ---------------------------------------------------------------------------
extern "C" void kernel_launch(void* const* d_in, const int* in_sizes, int n_in,
                              void* d_out, int out_size, void* d_ws, size_t ws_size,
                              hipStream_t stream) {
    const float* x  = (const float*)d_in[0];
    const float* W1 = (const float*)d_in[1];
    const float* b1 = (const float*)d_in[2];
    const float* Wq = (const float*)d_in[3];
    const float* Wk = (const float*)d_in[4];
    const float* Wv = (const float*)d_in[5];
    const float* bv = (const float*)d_in[6];
    const float* W2 = (const float*)d_in[7];
    const float* b2 = (const float*)d_in[8];
    const float* W3 = (const float*)d_in[9];
    const float* b3 = (const float*)d_in[10];
    const float* pe = (const float*)d_in[11];

    float* out  = (float*)d_out;             // (B,S,2)
    float* wout = out + (size_t)P_ * OUT_;   // (B,S,1,5)

    ushort* W1T  = (ushort*)d_ws;            // [128][128] bf16
    ushort* WqkT = W1T + 16384;              // [128][128] bf16
    ushort* WvT  = WqkT + 16384;             // [128][128] bf16
    ushort* W2T  = WvT + 16384;              // [32][128]  bf16

    prep_kernel<<<160, 256, 0, stream>>>(W1, Wv, W2, Wq, Wk, W1T, WvT, W2T, WqkT);
    fused_kernel<<<B_, 512, 0, stream>>>(x, W1T, WqkT, WvT, W2T,
                                         b1, bv, b2, W3, b3, pe, out, wout);
}